// Round 4
// baseline (138.864 us; speedup 1.0000x reference)
//
#include <hip/hip_runtime.h>
#include <hip/hip_fp16.h>

#define ODIM 128
#define INV_KEEP 1.1111112f   // float(1.0/0.9)

typedef float f4 __attribute__((ext_vector_type(4)));

// ---------- Fused prep kernel ----------
// Blocks [0, cvt_blocks): convert f32 W -> f16 into workspace (4 elems/thread).
// Blocks [cvt_blocks, ...): build CSR row_ptr from sorted rows[] by scatter.
// (Workspace is re-poisoned by the harness each replay, so no skip flag.)
__global__ void prep_kernel(const float* __restrict__ w, __half* __restrict__ wh,
                            int w_elems,
                            const int* __restrict__ rows, int* __restrict__ row_ptr,
                            int nnz, int n_nodes, int cvt_blocks) {
    if ((int)blockIdx.x < cvt_blocks) {
        int i4 = (blockIdx.x * 256 + threadIdx.x) * 4;
        if (i4 + 3 < w_elems) {
            float4 f = *(const float4*)(w + i4);
            *(__half2*)(wh + i4)     = __floats2half2_rn(f.x, f.y);
            *(__half2*)(wh + i4 + 2) = __floats2half2_rn(f.z, f.w);
        } else {
            for (int k = i4; k < w_elems; ++k) wh[k] = __float2half(w[k]);
        }
    } else {
        int i4 = ((blockIdx.x - cvt_blocks) * 256 + threadIdx.x) * 4;
        if (i4 >= nnz) return;
        int rprev = (i4 == 0) ? -1 : rows[i4 - 1];
        #pragma unroll
        for (int k = 0; k < 4; ++k) {
            int i = i4 + k;
            if (i < nnz) {
                int rc = rows[i];
                for (int r = rprev + 1; r <= rc; ++r) row_ptr[r] = i;
                if (i == nnz - 1)
                    for (int r = rc + 1; r <= n_nodes; ++r) row_ptr[r] = nnz;
                rprev = rc;
            }
        }
    }
}

// ---------- FMA helpers ----------
__device__ __forceinline__ void fma8h(float v, const uint4& h, float (&acc)[8]) {
    const __half2* hh = (const __half2*)&h;
    #pragma unroll
    for (int j = 0; j < 4; ++j) {    // fpext(f16)->fma fuses into v_fma_mix_f32
        acc[2*j]   = fmaf(v, __half2float(__low2half(hh[j])),  acc[2*j]);
        acc[2*j+1] = fmaf(v, __half2float(__high2half(hh[j])), acc[2*j+1]);
    }
}
__device__ __forceinline__ void fma8f(float v, const uint4& a, const uint4& b,
                                      float (&acc)[8]) {
    const float4 fa = *(const float4*)&a;
    const float4 fb = *(const float4*)&b;
    acc[0] = fmaf(v, fa.x, acc[0]);  acc[1] = fmaf(v, fa.y, acc[1]);
    acc[2] = fmaf(v, fa.z, acc[2]);  acc[3] = fmaf(v, fa.w, acc[3]);
    acc[4] = fmaf(v, fb.x, acc[4]);  acc[5] = fmaf(v, fb.y, acc[5]);
    acc[6] = fmaf(v, fb.z, acc[6]);  acc[7] = fmaf(v, fb.w, acc[7]);
}

// ---------- pipelined gather stages ----------
// Per call: read 4 cv (ds_read_b64, broadcast within a quarter) and issue the
// 4 matching gathers (global_load_dwordx4; 4 quarters x 256B = 1KB / instr).
// No predicates: stage pre-zeroes v and clamps c to 0 for pad slots.
template <typename WT>
__device__ __forceinline__ void gat4(const uint2* __restrict__ cvb, int lb, int js,
                                     const char* __restrict__ wbase, unsigned lo,
                                     uint2 (&cv)[4], uint4 (&ha)[4], uint4 (&hb)[4]) {
    cv[0] = cvb[lb + js];      cv[1] = cvb[lb + js + 2];
    cv[2] = cvb[lb + js + 4];  cv[3] = cvb[lb + js + 6];
    if constexpr (sizeof(WT) == 2) {
        ha[0] = *(const uint4*)(wbase + ((cv[0].x << 8) | lo));
        ha[1] = *(const uint4*)(wbase + ((cv[1].x << 8) | lo));
        ha[2] = *(const uint4*)(wbase + ((cv[2].x << 8) | lo));
        ha[3] = *(const uint4*)(wbase + ((cv[3].x << 8) | lo));
    } else {
        const unsigned o0 = (cv[0].x << 9) | lo;
        const unsigned o1 = (cv[1].x << 9) | lo;
        const unsigned o2 = (cv[2].x << 9) | lo;
        const unsigned o3 = (cv[3].x << 9) | lo;
        ha[0] = *(const uint4*)(wbase + o0);  hb[0] = *(const uint4*)(wbase + o0 + 16);
        ha[1] = *(const uint4*)(wbase + o1);  hb[1] = *(const uint4*)(wbase + o1 + 16);
        ha[2] = *(const uint4*)(wbase + o2);  hb[2] = *(const uint4*)(wbase + o2 + 16);
        ha[3] = *(const uint4*)(wbase + o3);  hb[3] = *(const uint4*)(wbase + o3 + 16);
    }
}
template <typename WT>
__device__ __forceinline__ void cons4(const uint2 (&cv)[4], const uint4 (&ha)[4],
                                      const uint4 (&hb)[4], float (&acc)[8]) {
    if constexpr (sizeof(WT) == 2) {
        fma8h(__uint_as_float(cv[0].y), ha[0], acc);
        fma8h(__uint_as_float(cv[1].y), ha[1], acc);
        fma8h(__uint_as_float(cv[2].y), ha[2], acc);
        fma8h(__uint_as_float(cv[3].y), ha[3], acc);
    } else {
        fma8f(__uint_as_float(cv[0].y), ha[0], hb[0], acc);
        fma8f(__uint_as_float(cv[1].y), ha[1], hb[1], acc);
        fma8f(__uint_as_float(cv[2].y), ha[2], hb[2], acc);
        fma8f(__uint_as_float(cv[3].y), ha[3], hb[3], acc);
    }
}

// ---------- Main SpMM: one wave = two rows, half-wave per row ----------
// Lanes 0-31 own row r0, lanes 32-63 own r0+1; the two rows advance in the
// SAME pipelined iterations (step 8 slots/row/iter, 2 quarters x unroll-4),
// so their latency chains overlap and ceil-waste is per-8 not per-16.
// Double-buffered cv/h: iteration j+1's gathers issue before iteration j's
// FMAs, keeping 4-8 dwordx4 in flight continuously.
template <typename WT>
__global__ void __launch_bounds__(256, 5)
spmm_kernel(const float* __restrict__ vals,
            const int*   __restrict__ rows,
            const int*   __restrict__ cols,
            const int*   __restrict__ mask,
            const WT*    __restrict__ wmat,
            const float* __restrict__ bias,
            const int*   __restrict__ row_ptr,   // may be null -> binary search
            float*       __restrict__ out,
            int nnz, int n_nodes) {
    __shared__ uint2 cvbuf[256];                 // per wave: [2 halves][32 slots]
    const int wave = threadIdx.x >> 6;
    const int lane = threadIdx.x & 63;
    const int h    = lane >> 5;                  // half: which row
    const int l31  = lane & 31;
    const int qq   = (lane >> 4) & 1;            // quarter within half
    const int s    = lane & 15;                  // sublane within quarter
    const int r0   = (blockIdx.x * 4 + wave) * 2;
    if (r0 >= n_nodes) return;

    int o0, o1, o2;                              // row_ptr[r0 .. r0+2]
    if (row_ptr) {
        int li = r0 + (lane < 2 ? (int)lane : 2);
        li = li < n_nodes ? li : n_nodes;
        const int t = row_ptr[li];               // one wave-load, 3 distinct addrs
        o0 = __builtin_amdgcn_readlane(t, 0);
        o1 = __builtin_amdgcn_readlane(t, 1);
        o2 = __builtin_amdgcn_readlane(t, 2);
    } else {
        auto lb_srch = [&](int target) {
            int lo = 0, hi = nnz;
            while (lo < hi) {
                int mid = (lo + hi) >> 1;
                if (rows[mid] < target) lo = mid + 1; else hi = mid;
            }
            return lo;
        };
        o0 = __builtin_amdgcn_readfirstlane(lb_srch(r0));
        o1 = __builtin_amdgcn_readfirstlane(lb_srch(r0 + 1));
        o2 = __builtin_amdgcn_readfirstlane(lb_srch(r0 + 2));
    }

    float acc[8] = {0.f,0.f,0.f,0.f,0.f,0.f,0.f,0.f};
    uint2* cvb = &cvbuf[wave << 6];
    const char* wbase = (const char*)wmat;
    const unsigned lo16 = (sizeof(WT) == 2) ? ((unsigned)s << 4)
                                            : ((unsigned)s << 5);
    const int lb = (h << 5) | qq;                // lds slot base for this lane

    int rem0 = o1 - o0, rem1 = o2 - o1;          // SGPR-uniform
    int cur  = (h ? o1 : o0) + l31;              // per-lane stage index
    const int endh = h ? o2 : o1;

    while (rem0 > 0 || rem1 > 0) {
        // ---- stage up to 32 nnz per half into LDS (pad: c=0, v=0) ----
        const bool valid = cur < endh;
        const int  a  = valid ? cur : 0;
        const int   c = __builtin_nontemporal_load(cols + a);
        const float vv = __builtin_nontemporal_load(vals + a);
        const int   m = __builtin_nontemporal_load(mask + a);
        const unsigned c_st = valid ? (unsigned)c : 0u;
        const float    v_st = (valid && m) ? vv * INV_KEEP : 0.0f;
        cvb[(h << 5) | l31] = make_uint2(c_st, __float_as_uint(v_st));
        // (same-wave ds_write -> ds_read ordered by the LDS pipe; no barrier)

        const int m0 = rem0 < 32 ? rem0 : 32;
        const int m1 = rem1 < 32 ? rem1 : 32;
        const int kmax = m0 > m1 ? m0 : m1;
        const int iters = (kmax + 7) >> 3;       // SGPR-uniform trip count

        uint2 cvA[4], cvB[4];
        uint4 hA[4], hB[4], gA[4], gB[4];        // gX dead for f16 (DCE'd)
        gat4<WT>(cvb, lb, 0, wbase, lo16, cvA, hA, gA);
        int j = 0;
        while (true) {
            if (j + 1 < iters) gat4<WT>(cvb, lb, (j + 1) * 8, wbase, lo16, cvB, hB, gB);
            cons4<WT>(cvA, hA, gA, acc);
            if (++j >= iters) break;
            if (j + 1 < iters) gat4<WT>(cvb, lb, (j + 1) * 8, wbase, lo16, cvA, hA, gA);
            cons4<WT>(cvB, hB, gB, acc);
            if (++j >= iters) break;
        }

        cur += 32;
        rem0 = rem0 > 32 ? rem0 - 32 : 0;
        rem1 = rem1 > 32 ? rem1 - 32 : 0;
    }

    // ---- reduce within half (combine the two quarters) and store ----
    #pragma unroll
    for (int j = 0; j < 8; ++j) acc[j] += __shfl_xor(acc[j], 16);
    // qq=0 lanes store cols 8s..8s+3, qq=1 lanes store cols 8s+4..8s+7
    const float e0 = qq ? acc[4] : acc[0];
    const float e1 = qq ? acc[5] : acc[1];
    const float e2 = qq ? acc[6] : acc[2];
    const float e3 = qq ? acc[7] : acc[3];
    const int cb = 8 * s + 4 * qq;
    const int row = r0 + h;
    if (row < n_nodes) {
        const float4 b = ((const float4*)bias)[(unsigned)cb >> 2];
        f4 o;
        o.x = e0 + b.x;  o.y = e1 + b.y;  o.z = e2 + b.z;  o.w = e3 + b.w;
        __builtin_nontemporal_store(o, (f4*)(out + (size_t)row * ODIM + cb));
    }
}

extern "C" void kernel_launch(void* const* d_in, const int* in_sizes, int n_in,
                              void* d_out, int out_size, void* d_ws, size_t ws_size,
                              hipStream_t stream) {
    const float* vals = (const float*)d_in[0];
    const int*   rows = (const int*)  d_in[1];
    const int*   cols = (const int*)  d_in[2];
    const int*   mask = (const int*)  d_in[3];
    const float* W    = (const float*)d_in[4];
    const float* bias = (const float*)d_in[5];
    float*       out  = (float*)d_out;

    const int nnz     = in_sizes[0];
    const int w_elems = in_sizes[4];             // INPUT_DIM * OUTPUT_DIM
    const int n_nodes = out_size / ODIM;

    // workspace layout: [W as f16 (256B aligned) | row_ptr (n_nodes+1 ints)]
    const size_t wh_bytes = ((size_t)w_elems * sizeof(__half) + 255) & ~(size_t)255;
    const size_t rp_bytes = (size_t)(n_nodes + 1) * sizeof(int);

    __half* wh = nullptr;
    int* row_ptr = nullptr;
    if (ws_size >= wh_bytes + rp_bytes) {
        wh = (__half*)d_ws;
        row_ptr = (int*)((char*)d_ws + wh_bytes);
    } else if (ws_size >= rp_bytes) {
        row_ptr = (int*)d_ws;
    }

    const int cvt_blocks = wh ? (w_elems / 4 + 255) / 256 : 0;
    const int rp_blocks  = row_ptr ? ((nnz + 3) / 4 + 255) / 256 : 0;
    if (cvt_blocks + rp_blocks > 0)
        prep_kernel<<<cvt_blocks + rp_blocks, 256, 0, stream>>>(
            W, wh, w_elems, rows, row_ptr, nnz, n_nodes, cvt_blocks);

    const int blocks = (n_nodes + 7) / 8;   // 8 rows (4 waves x 2 rows) per block
    if (wh) {
        spmm_kernel<__half><<<blocks, 256, 0, stream>>>(
            vals, rows, cols, mask, wh, bias, row_ptr, out, nnz, n_nodes);
    } else {
        spmm_kernel<float><<<blocks, 256, 0, stream>>>(
            vals, rows, cols, mask, W, bias, row_ptr, out, nnz, n_nodes);
    }
}